// Round 2
// baseline (280.417 us; speedup 1.0000x reference)
//
#include <hip/hip_runtime.h>
#include <hip/hip_bf16.h>
#include <stdint.h>

#define NN 10000
#define NE 320000
#define NH 4

typedef __attribute__((ext_vector_type(8))) short s16x8;
typedef __attribute__((ext_vector_type(4))) float f32x4;

static __device__ __forceinline__ float b2f(unsigned short u) {
    union { unsigned int i; float f; } x; x.i = ((unsigned int)u) << 16; return x.f;
}
static __device__ __forceinline__ unsigned short f2b(float f) {
    unsigned int u = __float_as_uint(f);
    unsigned int r = (u + 0x7fffu + ((u >> 16) & 1u)) >> 16;
    return (unsigned short)r;
}
// read element i of a float tensor stored either as bf16 (isbf=1) or fp32
static __device__ __forceinline__ float ldf(const void* p, int i, int isbf) {
    return isbf ? b2f(((const unsigned short*)p)[i]) : ((const float*)p)[i];
}

// ---------------- dtype detection: bf16 vs fp32 storage ----------------
__global__ void k_detect(const unsigned short* __restrict__ hraw, int* __restrict__ flag) {
    __shared__ int sb[256];
    int t = threadIdx.x;
    int cnt = 0;
    for (int i = t; i < 8192; i += 256) {
        unsigned short u = hraw[i];
        int e = (u >> 7) & 0xFF;
        cnt += (e >= 97 && e <= 157) ? 1 : 0;   // |x| in [2^-30, 2^30]
    }
    sb[t] = cnt;
    __syncthreads();
    for (int o = 128; o > 0; o >>= 1) {
        if (t < o) sb[t] += sb[t + o];
        __syncthreads();
    }
    if (t == 0) flag[0] = (sb[0] >= 6963) ? 1 : 0;   // 85% of 8192
}

// ---------------- CSR build ----------------
__global__ void k_zero(int* __restrict__ p, int n) {
    int i = blockIdx.x * 256 + threadIdx.x;
    if (i < n) p[i] = 0;
}

__global__ void k_deg(const int* __restrict__ dst, int* __restrict__ deg, int e) {
    int i = blockIdx.x * 256 + threadIdx.x;
    if (i < e) atomicAdd(&deg[dst[i]], 1);
}

__global__ void k_scan(const int* __restrict__ deg, int* __restrict__ offs,
                       int* __restrict__ cursor, int n) {
    __shared__ int buf[1024];
    __shared__ int s_carry;
    int t = threadIdx.x;
    if (t == 0) s_carry = 0;
    __syncthreads();
    int nch = (n + 1023) / 1024;
    for (int c = 0; c < nch; ++c) {
        int i = c * 1024 + t;
        int v = (i < n) ? deg[i] : 0;
        buf[t] = v;
        __syncthreads();
        for (int off = 1; off < 1024; off <<= 1) {
            int x = (t >= off) ? buf[t - off] : 0;
            __syncthreads();
            buf[t] += x;
            __syncthreads();
        }
        int incl = buf[t];
        int excl = incl - v + s_carry;
        if (i < n) { offs[i] = excl; cursor[i] = excl; }
        int chunk_total = buf[1023];
        __syncthreads();
        if (t == 0) s_carry += chunk_total;
        __syncthreads();
    }
    if (t == 0) offs[n] = s_carry;
}

__global__ void k_scatter(const int* __restrict__ src, const int* __restrict__ dst,
                          int* __restrict__ cursor, int* __restrict__ csr_src, int e) {
    int i = blockIdx.x * 256 + threadIdx.x;
    if (i < e) {
        int slot = atomicAdd(&cursor[dst[i]], 1);
        csr_src[slot] = src[i];
    }
}

// ---------------- small-tensor canonicalization to bf16 ----------------
// canon layout (ushorts): al1[256]@0, ar1[256]@256, b1[256]@512,
//                         al2[64]@768, ar2[64]@832, b2[64]@896
__global__ void k_small(const void* al1, const void* ar1, const void* b1,
                        const void* al2, const void* ar2, const void* b2,
                        unsigned short* __restrict__ out, const int* __restrict__ flagp) {
    int t = blockIdx.x * 256 + threadIdx.x;
    int isbf = flagp[0];
    if (t < 256)      out[t] = f2b(ldf(al1, t, isbf) * 1.0f), out[t] = isbf ? ((const unsigned short*)al1)[t] : f2b(((const float*)al1)[t]);
    else if (t < 512) out[t] = isbf ? ((const unsigned short*)ar1)[t - 256] : f2b(((const float*)ar1)[t - 256]);
    else if (t < 768) out[t] = isbf ? ((const unsigned short*)b1)[t - 512]  : f2b(((const float*)b1)[t - 512]);
    else if (t < 832) out[t] = isbf ? ((const unsigned short*)al2)[t - 768] : f2b(((const float*)al2)[t - 768]);
    else if (t < 896) out[t] = isbf ? ((const unsigned short*)ar2)[t - 832] : f2b(((const float*)ar2)[t - 832]);
    else if (t < 960) out[t] = isbf ? ((const unsigned short*)b2)[t - 896]  : f2b(((const float*)b2)[t - 896]);
}

// ---------------- W transpose -> bf16: WT[n*K+k] = W[k*N+n] ----------------
__global__ void k_transpose(const void* __restrict__ W, unsigned short* __restrict__ WT,
                            int K, int N, const int* __restrict__ flagp) {
    int idx = blockIdx.x * 256 + threadIdx.x;
    if (idx >= K * N) return;
    int isbf = flagp[0];
    int n = idx / K, k = idx - n * K;
    WT[idx] = isbf ? ((const unsigned short*)W)[(size_t)k * N + n]
                   : f2b(((const float*)W)[(size_t)k * N + n]);
}

// ---------------- bf16 MFMA GEMM: C[M,N] = A[M,K] @ B[K,N]; BT is [N,K] bf16 ----------------
// A is bf16 if (flagp==nullptr || *flagp) else fp32. C written as bf16.
// block 256 = 4 waves; block tile 64x64; wave w -> rows w*16..+15, all 64 cols.
__global__ __launch_bounds__(256) void k_gemm(const void* __restrict__ A,
                                              const unsigned short* __restrict__ BT,
                                              unsigned short* __restrict__ C,
                                              int M, int N, int K,
                                              const int* __restrict__ flagp) {
    __shared__ short As[64 * 40];   // 40-short stride = 80B: 16B-aligned rows, <=2-way bank alias
    __shared__ short Bs[64 * 40];
    int t = threadIdx.x;
    int wave = t >> 6, lane = t & 63;
    int m0 = blockIdx.x * 64;
    int n0 = blockIdx.y * 64;
    int a_isbf = flagp ? flagp[0] : 1;
    f32x4 acc[4] = {};

    int srow = t >> 2;            // 0..63
    int schunk = (t & 3) * 8;     // element offset within 32-wide K slab
    int aRow = m0 + srow; if (aRow > M - 1) aRow = M - 1;   // clamp: C-stores are guarded
    int bRow = n0 + srow;         // N multiple of 64

    for (int k0 = 0; k0 < K; k0 += 32) {
        __syncthreads();
        if (a_isbf) {
            *(s16x8*)&As[srow * 40 + schunk] =
                *(const s16x8*)&((const unsigned short*)A)[(size_t)aRow * K + k0 + schunk];
        } else {
            const float* pf = &((const float*)A)[(size_t)aRow * K + k0 + schunk];
            float4 x0 = *(const float4*)pf;
            float4 x1 = *(const float4*)(pf + 4);
            s16x8 v;
            v[0] = (short)f2b(x0.x); v[1] = (short)f2b(x0.y);
            v[2] = (short)f2b(x0.z); v[3] = (short)f2b(x0.w);
            v[4] = (short)f2b(x1.x); v[5] = (short)f2b(x1.y);
            v[6] = (short)f2b(x1.z); v[7] = (short)f2b(x1.w);
            *(s16x8*)&As[srow * 40 + schunk] = v;
        }
        *(s16x8*)&Bs[srow * 40 + schunk] =
            *(const s16x8*)&BT[(size_t)bRow * K + k0 + schunk];
        __syncthreads();
        s16x8 af = *(const s16x8*)&As[(wave * 16 + (lane & 15)) * 40 + (lane >> 4) * 8];
#pragma unroll
        for (int nt = 0; nt < 4; ++nt) {
            s16x8 bf = *(const s16x8*)&Bs[(nt * 16 + (lane & 15)) * 40 + (lane >> 4) * 8];
            acc[nt] = __builtin_amdgcn_mfma_f32_16x16x32_bf16(af, bf, acc[nt], 0, 0, 0);
        }
    }
    int col0 = n0 + (lane & 15);
    int r0 = m0 + wave * 16 + (lane >> 4) * 4;
#pragma unroll
    for (int nt = 0; nt < 4; ++nt) {
        int col = col0 + nt * 16;
#pragma unroll
        for (int i = 0; i < 4; ++i) {
            int r = r0 + i;
            if (r < M) C[(size_t)r * N + col] = f2b(acc[nt][i]);
        }
    }
}

// ---------------- el/er: one wave per (node, head), D=64; feat is bf16 ----------------
__global__ void k_attn(const unsigned short* __restrict__ feat,
                       const unsigned short* __restrict__ al,
                       const unsigned short* __restrict__ ar,
                       float* __restrict__ el, float* __restrict__ er, int nnodes, int H) {
    int wave = threadIdx.x >> 6, lane = threadIdx.x & 63;
    int npb = 4 / H;
    int node = blockIdx.x * npb + wave / H;
    int head = wave - (wave / H) * H;
    if (node >= nnodes) return;
    float v = b2f(feat[((size_t)node * H + head) * 64 + lane]);
    float s1 = v * b2f(al[head * 64 + lane]);
    float s2 = v * b2f(ar[head * 64 + lane]);
    for (int off = 32; off > 0; off >>= 1) {
        s1 += __shfl_down(s1, off, 64);
        s2 += __shfl_down(s2, off, 64);
    }
    if (lane == 0) { el[node * H + head] = s1; er[node * H + head] = s2; }
}

// ---------------- layer-1 edges: block per dst, wave=head, lane=dim; ELU fused ----------------
__global__ void k_edge1(const int* __restrict__ offs, const int* __restrict__ csr_src,
                        const float* __restrict__ el, const float* __restrict__ er,
                        const unsigned short* __restrict__ feat,
                        const unsigned short* __restrict__ b1,
                        unsigned short* __restrict__ h1) {
    int node = blockIdx.x;
    int wave = threadIdx.x >> 6, lane = threadIdx.x & 63;
    int start = offs[node], end = offs[node + 1];
    float er_d = er[node * NH + wave];
    float m = -3.0e38f, l = 0.f, acc = 0.f;
    for (int e = start; e < end; ++e) {
        int s = csr_src[e];
        float x = el[s * NH + wave] + er_d;
        float ee = (x >= 0.f) ? x : 0.2f * x;
        float mn = fmaxf(m, ee);
        float sc = __expf(m - mn);
        float w = __expf(ee - mn);
        l = l * sc + w;
        acc = acc * sc + w * b2f(feat[(size_t)s * 256 + wave * 64 + lane]);
        m = mn;
    }
    float o = (l > 0.f) ? acc / l : 0.f;
    o += b2f(b1[wave * 64 + lane]);
    o = (o > 0.f) ? o : (__expf(o) - 1.f);   // ELU
    h1[(size_t)node * 256 + wave * 64 + lane] = f2b(o);
}

// ---------------- layer-2 edges: wave per dst (H=1, D=64); output dtype per flag ----------------
__global__ void k_edge2(const int* __restrict__ offs, const int* __restrict__ csr_src,
                        const float* __restrict__ el, const float* __restrict__ er,
                        const unsigned short* __restrict__ feat,
                        const unsigned short* __restrict__ b2,
                        void* __restrict__ out, const int* __restrict__ flagp) {
    int wave = threadIdx.x >> 6, lane = threadIdx.x & 63;
    int node = blockIdx.x * 4 + wave;
    if (node >= NN) return;
    int isbf = flagp[0];
    int start = offs[node], end = offs[node + 1];
    float er_d = er[node];
    float m = -3.0e38f, l = 0.f, acc = 0.f;
    for (int e = start; e < end; ++e) {
        int s = csr_src[e];
        float x = el[s] + er_d;
        float ee = (x >= 0.f) ? x : 0.2f * x;
        float mn = fmaxf(m, ee);
        float sc = __expf(m - mn);
        float w = __expf(ee - mn);
        l = l * sc + w;
        acc = acc * sc + w * b2f(feat[(size_t)s * 64 + lane]);
        m = mn;
    }
    float o = (l > 0.f) ? acc / l : 0.f;
    o += b2f(b2[lane]);
    size_t oi = (size_t)node * 64 + lane;
    if (isbf) ((unsigned short*)out)[oi] = f2b(o);
    else      ((float*)out)[oi] = o;
}

extern "C" void kernel_launch(void* const* d_in, const int* in_sizes, int n_in,
                              void* d_out, int out_size, void* d_ws, size_t ws_size,
                              hipStream_t stream) {
    const void* h   = d_in[0];               // [10000,256] bf16 or fp32 (detected)
    const int*  src = (const int*)d_in[1];
    const int*  dst = (const int*)d_in[2];
    const void* W1  = d_in[3];               // [256,256]
    const void* al1 = d_in[4];               // [4,64]
    const void* ar1 = d_in[5];
    const void* b1  = d_in[6];               // [256]
    const void* W2  = d_in[7];               // [256,64]
    const void* al2 = d_in[8];               // [1,64]
    const void* ar2 = d_in[9];
    const void* b2  = d_in[10];              // [64]

    char* w = (char*)d_ws;
    size_t off = 0;
    auto alloc = [&](size_t bytes) -> void* {
        void* p = w + off;
        off = (off + bytes + 255) & ~(size_t)255;
        return p;
    };
    int* flag               = (int*)alloc(4);
    int* deg                = (int*)alloc(NN * 4);
    int* cursor             = (int*)alloc(NN * 4);
    int* offs               = (int*)alloc((NN + 1) * 4);
    int* csr_src            = (int*)alloc(NE * 4);
    unsigned short* canon   = (unsigned short*)alloc(960 * 2);
    unsigned short* W1T     = (unsigned short*)alloc(256 * 256 * 2);
    unsigned short* W2T     = (unsigned short*)alloc(64 * 256 * 2);
    unsigned short* feat1   = (unsigned short*)alloc((size_t)NN * 256 * 2);  // bf16 [N,4,64]
    float* el1              = (float*)alloc(NN * NH * 4);
    float* er1              = (float*)alloc(NN * NH * 4);
    unsigned short* h1      = (unsigned short*)alloc((size_t)NN * 256 * 2);  // bf16
    unsigned short* feat2   = (unsigned short*)alloc((size_t)NN * 64 * 2);   // bf16
    float* el2              = (float*)alloc(NN * 4);
    float* er2              = (float*)alloc(NN * 4);
    (void)ws_size; (void)in_sizes; (void)n_in; (void)out_size;

    unsigned short* cal1 = canon + 0;
    unsigned short* car1 = canon + 256;
    unsigned short* cb1  = canon + 512;
    unsigned short* cal2 = canon + 768;
    unsigned short* car2 = canon + 832;
    unsigned short* cb2  = canon + 896;

    // dtype detection
    k_detect<<<1, 256, 0, stream>>>((const unsigned short*)h, flag);

    // CSR build
    k_zero<<<(NN + 255) / 256, 256, 0, stream>>>(deg, NN);
    k_deg<<<(NE + 255) / 256, 256, 0, stream>>>(dst, deg, NE);
    k_scan<<<1, 1024, 0, stream>>>(deg, offs, cursor, NN);
    k_scatter<<<(NE + 255) / 256, 256, 0, stream>>>(src, dst, cursor, csr_src, NE);

    // canonicalize small tensors + weight transposes (bf16 output)
    k_small<<<4, 256, 0, stream>>>(al1, ar1, b1, al2, ar2, b2, canon, flag);
    k_transpose<<<(256 * 256 + 255) / 256, 256, 0, stream>>>(W1, W1T, 256, 256, flag);
    k_transpose<<<(256 * 64 + 255) / 256, 256, 0, stream>>>(W2, W2T, 256, 64, flag);

    // layer 1
    k_gemm<<<dim3((NN + 63) / 64, 256 / 64), 256, 0, stream>>>(h, W1T, feat1, NN, 256, 256, flag);
    k_attn<<<NN, 256, 0, stream>>>(feat1, cal1, car1, el1, er1, NN, NH);
    k_edge1<<<NN, 256, 0, stream>>>(offs, csr_src, el1, er1, feat1, cb1, h1);

    // layer 2
    k_gemm<<<dim3((NN + 63) / 64, 64 / 64), 256, 0, stream>>>(h1, W2T, feat2, NN, 64, 256, nullptr);
    k_attn<<<(NN + 3) / 4, 256, 0, stream>>>(feat2, cal2, car2, el2, er2, NN, 1);
    k_edge2<<<(NN + 3) / 4, 256, 0, stream>>>(offs, csr_src, el2, er2, feat2, cb2, d_out, flag);
}

// Round 3
// 261.404 us; speedup vs baseline: 1.0727x; 1.0727x over previous
//
#include <hip/hip_runtime.h>
#include <hip/hip_bf16.h>
#include <stdint.h>

#define NN 10000
#define NE 320000
#define NH 4

typedef __attribute__((ext_vector_type(8))) short s16x8;
typedef __attribute__((ext_vector_type(4))) float f32x4;

static __device__ __forceinline__ float b2f(unsigned short u) {
    union { unsigned int i; float f; } x; x.i = ((unsigned int)u) << 16; return x.f;
}
static __device__ __forceinline__ unsigned short f2b(float f) {
    unsigned int u = __float_as_uint(f);
    unsigned int r = (u + 0x7fffu + ((u >> 16) & 1u)) >> 16;
    return (unsigned short)r;
}

// ---------------- dtype detection: bf16 vs fp32 storage ----------------
__global__ void k_detect(const unsigned short* __restrict__ hraw, int* __restrict__ flag) {
    __shared__ int sb[256];
    int t = threadIdx.x;
    int cnt = 0;
    for (int i = t; i < 8192; i += 256) {
        unsigned short u = hraw[i];
        int e = (u >> 7) & 0xFF;
        cnt += (e >= 97 && e <= 157) ? 1 : 0;   // |x| in [2^-30, 2^30]
    }
    sb[t] = cnt;
    __syncthreads();
    for (int o = 128; o > 0; o >>= 1) {
        if (t < o) sb[t] += sb[t + o];
        __syncthreads();
    }
    if (t == 0) flag[0] = (sb[0] >= 6963) ? 1 : 0;   // 85% of 8192
}

// ---------------- CSR build ----------------
__global__ void k_deg(const int* __restrict__ dst, int* __restrict__ deg, int e) {
    int i = blockIdx.x * 256 + threadIdx.x;
    if (i < e) atomicAdd(&deg[dst[i]], 1);
}

// single block, 256 threads, 40 contiguous elements per thread (256*40 >= NN)
__global__ void k_scan(const int* __restrict__ deg, int* __restrict__ offs,
                       int* __restrict__ cursor, int n) {
    __shared__ int wtot[4];
    int t = threadIdx.x;
    int lane = t & 63, wv = t >> 6;
    int base = t * 40;
    int sum = 0;
#pragma unroll
    for (int j = 0; j < 40; ++j) {
        int i = base + j;
        sum += (i < n) ? deg[i] : 0;
    }
    int x = sum;
    for (int o = 1; o < 64; o <<= 1) {
        int y = __shfl_up(x, o, 64);
        if (lane >= o) x += y;
    }
    if (lane == 63) wtot[wv] = x;
    __syncthreads();
    int wbase = 0;
    for (int k = 0; k < wv; ++k) wbase += wtot[k];
    int run = wbase + x - sum;   // exclusive prefix for this thread's chunk
    for (int j = 0; j < 40; ++j) {
        int i = base + j;
        if (i < n) {
            offs[i] = run;
            cursor[i] = run;
            run += deg[i];
        }
    }
    if (t == 255) offs[n] = run;
}

__global__ void k_scatter(const int* __restrict__ src, const int* __restrict__ dst,
                          int* __restrict__ cursor, int* __restrict__ csr_src, int e) {
    int i = blockIdx.x * 256 + threadIdx.x;
    if (i < e) {
        int slot = atomicAdd(&cursor[dst[i]], 1);
        csr_src[slot] = src[i];
    }
}

// ---------------- small-tensor canonicalization to bf16 ----------------
// canon (ushorts): al1[256]@0, ar1[256]@256, b1[256]@512, al2[64]@768, ar2[64]@832, b2[64]@896
__global__ void k_small(const void* al1, const void* ar1, const void* b1,
                        const void* al2, const void* ar2, const void* b2,
                        unsigned short* __restrict__ out, const int* __restrict__ flagp) {
    int t = blockIdx.x * 256 + threadIdx.x;
    int isbf = flagp[0];
    const void* srcp; int idx;
    if      (t < 256) { srcp = al1; idx = t; }
    else if (t < 512) { srcp = ar1; idx = t - 256; }
    else if (t < 768) { srcp = b1;  idx = t - 512; }
    else if (t < 832) { srcp = al2; idx = t - 768; }
    else if (t < 896) { srcp = ar2; idx = t - 832; }
    else if (t < 960) { srcp = b2;  idx = t - 896; }
    else return;
    out[t] = isbf ? ((const unsigned short*)srcp)[idx] : f2b(((const float*)srcp)[idx]);
}

// ---------------- merged W transposes -> bf16: WT[n*K+k] = W[k*N+n] ----------------
__global__ void k_transpose_all(const void* __restrict__ W1, const void* __restrict__ W2,
                                unsigned short* __restrict__ W1T, unsigned short* __restrict__ W2T,
                                const int* __restrict__ flagp) {
    int idx = blockIdx.x * 256 + threadIdx.x;
    int isbf = flagp[0];
    if (idx < 65536) {           // W1: K=256, N=256
        int n = idx >> 8, k = idx & 255;
        W1T[idx] = isbf ? ((const unsigned short*)W1)[(size_t)k * 256 + n]
                        : f2b(((const float*)W1)[(size_t)k * 256 + n]);
    } else if (idx < 65536 + 16384) {   // W2: K=256, N=64
        int j = idx - 65536;
        int n = j >> 8, k = j & 255;
        W2T[j] = isbf ? ((const unsigned short*)W2)[(size_t)k * 64 + n]
                      : f2b(((const float*)W2)[(size_t)k * 64 + n]);
    }
}

// ---------------- bf16 MFMA GEMM + fused el/er epilogue ----------------
// C[M,N] = A[M,K] @ B[K,N]; BT is [N,K] bf16. Block tile 64x64; blockIdx.y = head
// (layer1: N=256, H=4, 64 cols per head; layer2: N=64, H=1).
// Epilogue also writes el[r*H+head] = sum_d feat*al, er likewise.
__global__ __launch_bounds__(256) void k_gemm(const void* __restrict__ A,
                                              const unsigned short* __restrict__ BT,
                                              unsigned short* __restrict__ C,
                                              float* __restrict__ el, float* __restrict__ er,
                                              const unsigned short* __restrict__ al,
                                              const unsigned short* __restrict__ ar,
                                              int M, int N, int K, int H,
                                              const int* __restrict__ flagp) {
    __shared__ short As[64 * 40];   // 40-short stride = 80B rows: 16B-aligned, <=2-way bank alias
    __shared__ short Bs[64 * 40];
    int t = threadIdx.x;
    int wave = t >> 6, lane = t & 63;
    int m0 = blockIdx.x * 64;
    int head = blockIdx.y;
    int n0 = head * 64;
    int a_isbf = flagp ? flagp[0] : 1;
    f32x4 acc[4] = {};

    int srow = t >> 2;
    int schunk = (t & 3) * 8;
    int aRow = m0 + srow; if (aRow > M - 1) aRow = M - 1;   // clamp; stores guarded
    int bRow = n0 + srow;

    for (int k0 = 0; k0 < K; k0 += 32) {
        __syncthreads();
        if (a_isbf) {
            *(s16x8*)&As[srow * 40 + schunk] =
                *(const s16x8*)&((const unsigned short*)A)[(size_t)aRow * K + k0 + schunk];
        } else {
            const float* pf = &((const float*)A)[(size_t)aRow * K + k0 + schunk];
            float4 x0 = *(const float4*)pf;
            float4 x1 = *(const float4*)(pf + 4);
            s16x8 v;
            v[0] = (short)f2b(x0.x); v[1] = (short)f2b(x0.y);
            v[2] = (short)f2b(x0.z); v[3] = (short)f2b(x0.w);
            v[4] = (short)f2b(x1.x); v[5] = (short)f2b(x1.y);
            v[6] = (short)f2b(x1.z); v[7] = (short)f2b(x1.w);
            *(s16x8*)&As[srow * 40 + schunk] = v;
        }
        *(s16x8*)&Bs[srow * 40 + schunk] =
            *(const s16x8*)&BT[(size_t)bRow * K + k0 + schunk];
        __syncthreads();
        s16x8 af = *(const s16x8*)&As[(wave * 16 + (lane & 15)) * 40 + (lane >> 4) * 8];
#pragma unroll
        for (int nt = 0; nt < 4; ++nt) {
            s16x8 bf = *(const s16x8*)&Bs[(nt * 16 + (lane & 15)) * 40 + (lane >> 4) * 8];
            acc[nt] = __builtin_amdgcn_mfma_f32_16x16x32_bf16(af, bf, acc[nt], 0, 0, 0);
        }
    }

    // store C (bf16) — round first so el/er match what k_edge* re-reads
    int col0 = n0 + (lane & 15);
    int r0 = m0 + wave * 16 + (lane >> 4) * 4;
    float cr[4][4];
#pragma unroll
    for (int nt = 0; nt < 4; ++nt) {
        int col = col0 + nt * 16;
#pragma unroll
        for (int i = 0; i < 4; ++i) {
            unsigned short cb = f2b(acc[nt][i]);
            cr[nt][i] = b2f(cb);
            int r = r0 + i;
            if (r < M) C[(size_t)r * N + col] = cb;
        }
    }

    // fused el/er: per-row dot with al/ar over this head's 64 cols
    float alv[4], arv[4];
#pragma unroll
    for (int nt = 0; nt < 4; ++nt) {
        int c = (lane & 15) + nt * 16;         // col within head
        alv[nt] = b2f(al[head * 64 + c]);
        arv[nt] = b2f(ar[head * 64 + c]);
    }
#pragma unroll
    for (int i = 0; i < 4; ++i) {
        float pl = 0.f, pr = 0.f;
#pragma unroll
        for (int nt = 0; nt < 4; ++nt) {
            pl += cr[nt][i] * alv[nt];
            pr += cr[nt][i] * arv[nt];
        }
#pragma unroll
        for (int o = 1; o < 16; o <<= 1) {     // reduce across the 16-lane col group
            pl += __shfl_xor(pl, o, 64);
            pr += __shfl_xor(pr, o, 64);
        }
        int r = r0 + i;
        if ((lane & 15) == 0 && r < M) {
            el[(size_t)r * H + head] = pl;
            er[(size_t)r * H + head] = pr;
        }
    }
}

// ---------------- layer-1 edges: block per dst, wave=head ----------------
// lanes parallelize edges for csr/el/exp; broadcast loop accumulates feat (lane=dim)
__global__ __launch_bounds__(256) void k_edge1(const int* __restrict__ offs,
                        const int* __restrict__ csr_src,
                        const float* __restrict__ el, const float* __restrict__ er,
                        const unsigned short* __restrict__ feat,
                        const unsigned short* __restrict__ b1,
                        unsigned short* __restrict__ h1) {
    int node = blockIdx.x;
    int head = threadIdx.x >> 6, lane = threadIdx.x & 63;
    int start = offs[node], end = offs[node + 1];
    float er_d = er[node * NH + head];
    float l = 0.f, acc = 0.f;
    for (int base = start; base < end; base += 64) {
        int c = base + lane;
        float wgt = 0.f; int s = 0;
        if (c < end) {
            s = csr_src[c];
            float x = el[s * NH + head] + er_d;
            x = (x >= 0.f) ? x : 0.2f * x;
            wgt = __expf(x);          // |x| ~ O(1): no max-shift needed (shift-invariant)
        }
        l += wgt;
        int cnt = end - base; if (cnt > 64) cnt = 64;
#pragma unroll 4
        for (int e = 0; e < cnt; ++e) {
            float we = __shfl(wgt, e, 64);
            int se = __shfl(s, e, 64);
            acc += we * b2f(feat[(((size_t)se * NH + head) << 6) + lane]);
        }
    }
    for (int o = 32; o > 0; o >>= 1) l += __shfl_xor(l, o, 64);
    float o = (l > 0.f) ? acc / l : 0.f;
    o += b2f(b1[head * 64 + lane]);
    o = (o > 0.f) ? o : (__expf(o) - 1.f);   // ELU
    h1[(((size_t)node * NH + head) << 6) + lane] = f2b(o);
}

// ---------------- layer-2 edges: wave per dst (H=1, D=64) ----------------
__global__ __launch_bounds__(256) void k_edge2(const int* __restrict__ offs,
                        const int* __restrict__ csr_src,
                        const float* __restrict__ el, const float* __restrict__ er,
                        const unsigned short* __restrict__ feat,
                        const unsigned short* __restrict__ b2,
                        void* __restrict__ out, const int* __restrict__ flagp) {
    int wave = threadIdx.x >> 6, lane = threadIdx.x & 63;
    int node = blockIdx.x * 4 + wave;
    if (node >= NN) return;
    int isbf = flagp[0];
    int start = offs[node], end = offs[node + 1];
    float er_d = er[node];
    float l = 0.f, acc = 0.f;
    for (int base = start; base < end; base += 64) {
        int c = base + lane;
        float wgt = 0.f; int s = 0;
        if (c < end) {
            s = csr_src[c];
            float x = el[s] + er_d;
            x = (x >= 0.f) ? x : 0.2f * x;
            wgt = __expf(x);
        }
        l += wgt;
        int cnt = end - base; if (cnt > 64) cnt = 64;
#pragma unroll 4
        for (int e = 0; e < cnt; ++e) {
            float we = __shfl(wgt, e, 64);
            int se = __shfl(s, e, 64);
            acc += we * b2f(feat[((size_t)se << 6) + lane]);
        }
    }
    for (int o = 32; o > 0; o >>= 1) l += __shfl_xor(l, o, 64);
    float o = (l > 0.f) ? acc / l : 0.f;
    o += b2f(b2[lane]);
    size_t oi = ((size_t)node << 6) + lane;
    if (isbf) ((unsigned short*)out)[oi] = f2b(o);
    else      ((float*)out)[oi] = o;
}

extern "C" void kernel_launch(void* const* d_in, const int* in_sizes, int n_in,
                              void* d_out, int out_size, void* d_ws, size_t ws_size,
                              hipStream_t stream) {
    const void* h   = d_in[0];               // [10000,256] bf16 (detected)
    const int*  src = (const int*)d_in[1];
    const int*  dst = (const int*)d_in[2];
    const void* W1  = d_in[3];               // [256,256]
    const void* al1 = d_in[4];
    const void* ar1 = d_in[5];
    const void* b1  = d_in[6];
    const void* W2  = d_in[7];               // [256,64]
    const void* al2 = d_in[8];
    const void* ar2 = d_in[9];
    const void* b2  = d_in[10];

    char* w = (char*)d_ws;
    size_t off = 0;
    auto alloc = [&](size_t bytes) -> void* {
        void* p = w + off;
        off = (off + bytes + 255) & ~(size_t)255;
        return p;
    };
    int* flag               = (int*)alloc(4);
    int* deg                = (int*)alloc(NN * 4);
    int* cursor             = (int*)alloc(NN * 4);
    int* offs               = (int*)alloc((NN + 1) * 4);
    int* csr_src            = (int*)alloc(NE * 4);
    unsigned short* canon   = (unsigned short*)alloc(960 * 2);
    unsigned short* W1T     = (unsigned short*)alloc(256 * 256 * 2);
    unsigned short* W2T     = (unsigned short*)alloc(64 * 256 * 2);
    unsigned short* feat1   = (unsigned short*)alloc((size_t)NN * 256 * 2);  // bf16 [N,4,64]
    float* el1              = (float*)alloc(NN * NH * 4);
    float* er1              = (float*)alloc(NN * NH * 4);
    unsigned short* h1      = (unsigned short*)alloc((size_t)NN * 256 * 2);  // bf16
    unsigned short* feat2   = (unsigned short*)alloc((size_t)NN * 64 * 2);   // bf16
    float* el2              = (float*)alloc(NN * 4);
    float* er2              = (float*)alloc(NN * 4);
    (void)ws_size; (void)in_sizes; (void)n_in; (void)out_size;

    unsigned short* cal1 = canon + 0;
    unsigned short* car1 = canon + 256;
    unsigned short* cb1  = canon + 512;
    unsigned short* cal2 = canon + 768;
    unsigned short* car2 = canon + 832;
    unsigned short* cb2  = canon + 896;

    k_detect<<<1, 256, 0, stream>>>((const unsigned short*)h, flag);

    hipMemsetAsync(deg, 0, NN * 4, stream);
    k_deg<<<(NE + 255) / 256, 256, 0, stream>>>(dst, deg, NE);
    k_scan<<<1, 256, 0, stream>>>(deg, offs, cursor, NN);
    k_scatter<<<(NE + 255) / 256, 256, 0, stream>>>(src, dst, cursor, csr_src, NE);

    k_small<<<4, 256, 0, stream>>>(al1, ar1, b1, al2, ar2, b2, canon, flag);
    k_transpose_all<<<(65536 + 16384 + 255) / 256, 256, 0, stream>>>(W1, W2, W1T, W2T, flag);

    // layer 1: GEMM + fused el/er, then edge softmax-aggregate (+ELU)
    k_gemm<<<dim3((NN + 63) / 64, 4), 256, 0, stream>>>(h, W1T, feat1, el1, er1,
                                                        cal1, car1, NN, 256, 256, NH, flag);
    k_edge1<<<NN, 256, 0, stream>>>(offs, csr_src, el1, er1, feat1, cb1, h1);

    // layer 2
    k_gemm<<<dim3((NN + 63) / 64, 1), 256, 0, stream>>>(h1, W2T, feat2, el2, er2,
                                                        cal2, car2, NN, 64, 256, 1, nullptr);
    k_edge2<<<(NN + 3) / 4, 256, 0, stream>>>(offs, csr_src, el2, er2, feat2, cb2, d_out, flag);
}

// Round 4
// 215.432 us; speedup vs baseline: 1.3017x; 1.2134x over previous
//
#include <hip/hip_runtime.h>
#include <hip/hip_bf16.h>
#include <stdint.h>

#define NN 10000
#define NE 320000
#define NH 4

typedef __attribute__((ext_vector_type(8))) short s16x8;
typedef __attribute__((ext_vector_type(4))) float f32x4;
typedef __attribute__((ext_vector_type(4))) unsigned short u16x4;

static __device__ __forceinline__ float b2f(unsigned short u) {
    union { unsigned int i; float f; } x; x.i = ((unsigned int)u) << 16; return x.f;
}
static __device__ __forceinline__ unsigned short f2b(float f) {
    unsigned int u = __float_as_uint(f);
    unsigned int r = (u + 0x7fffu + ((u >> 16) & 1u)) >> 16;
    return (unsigned short)r;
}

// ---------------- dtype detection: bf16 vs fp32 storage ----------------
__global__ void k_detect(const unsigned short* __restrict__ hraw, int* __restrict__ flag) {
    __shared__ int sb[256];
    int t = threadIdx.x;
    int cnt = 0;
    for (int i = t; i < 8192; i += 256) {
        unsigned short u = hraw[i];
        int e = (u >> 7) & 0xFF;
        cnt += (e >= 97 && e <= 157) ? 1 : 0;   // |x| in [2^-30, 2^30]
    }
    sb[t] = cnt;
    __syncthreads();
    for (int o = 128; o > 0; o >>= 1) {
        if (t < o) sb[t] += sb[t + o];
        __syncthreads();
    }
    if (t == 0) flag[0] = (sb[0] >= 6963) ? 1 : 0;   // 85% of 8192
}

// ---------------- CSR build ----------------
__global__ void k_deg(const int* __restrict__ dst, int* __restrict__ deg, int e) {
    int i = blockIdx.x * 256 + threadIdx.x;
    if (i < e) atomicAdd(&deg[dst[i]], 1);
}

// single block, 256 threads, 40 contiguous elements per thread (256*40 >= NN)
__global__ void k_scan(const int* __restrict__ deg, int* __restrict__ offs,
                       int* __restrict__ cursor, int n) {
    __shared__ int wtot[4];
    int t = threadIdx.x;
    int lane = t & 63, wv = t >> 6;
    int base = t * 40;
    int sum = 0;
#pragma unroll
    for (int j = 0; j < 40; ++j) {
        int i = base + j;
        sum += (i < n) ? deg[i] : 0;
    }
    int x = sum;
    for (int o = 1; o < 64; o <<= 1) {
        int y = __shfl_up(x, o, 64);
        if (lane >= o) x += y;
    }
    if (lane == 63) wtot[wv] = x;
    __syncthreads();
    int wbase = 0;
    for (int k = 0; k < wv; ++k) wbase += wtot[k];
    int run = wbase + x - sum;   // exclusive prefix for this thread's chunk
    for (int j = 0; j < 40; ++j) {
        int i = base + j;
        if (i < n) {
            offs[i] = run;
            cursor[i] = run;
            run += deg[i];
        }
    }
    if (t == 255) offs[n] = run;
}

__global__ void k_scatter(const int* __restrict__ src, const int* __restrict__ dst,
                          int* __restrict__ cursor, int* __restrict__ csr_src, int e) {
    int i = blockIdx.x * 256 + threadIdx.x;
    if (i < e) {
        int slot = atomicAdd(&cursor[dst[i]], 1);
        csr_src[slot] = src[i];
    }
}

// ---------------- small-tensor canonicalization to bf16 ----------------
__global__ void k_small(const void* al1, const void* ar1, const void* b1,
                        const void* al2, const void* ar2, const void* b2,
                        unsigned short* __restrict__ out, const int* __restrict__ flagp) {
    int t = blockIdx.x * 256 + threadIdx.x;
    int isbf = flagp[0];
    const void* srcp; int idx;
    if      (t < 256) { srcp = al1; idx = t; }
    else if (t < 512) { srcp = ar1; idx = t - 256; }
    else if (t < 768) { srcp = b1;  idx = t - 512; }
    else if (t < 832) { srcp = al2; idx = t - 768; }
    else if (t < 896) { srcp = ar2; idx = t - 832; }
    else if (t < 960) { srcp = b2;  idx = t - 896; }
    else return;
    out[t] = isbf ? ((const unsigned short*)srcp)[idx] : f2b(((const float*)srcp)[idx]);
}

// ---------------- merged W transposes -> bf16: WT[n*K+k] = W[k*N+n] ----------------
__global__ void k_transpose_all(const void* __restrict__ W1, const void* __restrict__ W2,
                                unsigned short* __restrict__ W1T, unsigned short* __restrict__ W2T,
                                const int* __restrict__ flagp) {
    int idx = blockIdx.x * 256 + threadIdx.x;
    int isbf = flagp[0];
    if (idx < 65536) {           // W1: K=256, N=256
        int n = idx >> 8, k = idx & 255;
        W1T[idx] = isbf ? ((const unsigned short*)W1)[(size_t)k * 256 + n]
                        : f2b(((const float*)W1)[(size_t)k * 256 + n]);
    } else if (idx < 65536 + 16384) {   // W2: K=256, N=64
        int j = idx - 65536;
        int n = j >> 8, k = j & 255;
        W2T[j] = isbf ? ((const unsigned short*)W2)[(size_t)k * 64 + n]
                      : f2b(((const float*)W2)[(size_t)k * 64 + n]);
    }
}

// ---------------- bf16 MFMA GEMM + fused el/er epilogue ----------------
__global__ __launch_bounds__(256) void k_gemm(const void* __restrict__ A,
                                              const unsigned short* __restrict__ BT,
                                              unsigned short* __restrict__ C,
                                              float* __restrict__ el, float* __restrict__ er,
                                              const unsigned short* __restrict__ al,
                                              const unsigned short* __restrict__ ar,
                                              int M, int N, int K, int H,
                                              const int* __restrict__ flagp) {
    __shared__ short As[64 * 40];   // 40-short stride = 80B rows: 16B-aligned, <=2-way alias
    __shared__ short Bs[64 * 40];
    int t = threadIdx.x;
    int wave = t >> 6, lane = t & 63;
    int m0 = blockIdx.x * 64;
    int head = blockIdx.y;
    int n0 = head * 64;
    int a_isbf = flagp ? flagp[0] : 1;
    f32x4 acc[4] = {};

    int srow = t >> 2;
    int schunk = (t & 3) * 8;
    int aRow = m0 + srow; if (aRow > M - 1) aRow = M - 1;   // clamp; stores guarded
    int bRow = n0 + srow;

    for (int k0 = 0; k0 < K; k0 += 32) {
        __syncthreads();
        if (a_isbf) {
            *(s16x8*)&As[srow * 40 + schunk] =
                *(const s16x8*)&((const unsigned short*)A)[(size_t)aRow * K + k0 + schunk];
        } else {
            const float* pf = &((const float*)A)[(size_t)aRow * K + k0 + schunk];
            float4 x0 = *(const float4*)pf;
            float4 x1 = *(const float4*)(pf + 4);
            s16x8 v;
            v[0] = (short)f2b(x0.x); v[1] = (short)f2b(x0.y);
            v[2] = (short)f2b(x0.z); v[3] = (short)f2b(x0.w);
            v[4] = (short)f2b(x1.x); v[5] = (short)f2b(x1.y);
            v[6] = (short)f2b(x1.z); v[7] = (short)f2b(x1.w);
            *(s16x8*)&As[srow * 40 + schunk] = v;
        }
        *(s16x8*)&Bs[srow * 40 + schunk] =
            *(const s16x8*)&BT[(size_t)bRow * K + k0 + schunk];
        __syncthreads();
        s16x8 af = *(const s16x8*)&As[(wave * 16 + (lane & 15)) * 40 + (lane >> 4) * 8];
#pragma unroll
        for (int nt = 0; nt < 4; ++nt) {
            s16x8 bf = *(const s16x8*)&Bs[(nt * 16 + (lane & 15)) * 40 + (lane >> 4) * 8];
            acc[nt] = __builtin_amdgcn_mfma_f32_16x16x32_bf16(af, bf, acc[nt], 0, 0, 0);
        }
    }

    int col0 = n0 + (lane & 15);
    int r0 = m0 + wave * 16 + (lane >> 4) * 4;
    float cr[4][4];
#pragma unroll
    for (int nt = 0; nt < 4; ++nt) {
        int col = col0 + nt * 16;
#pragma unroll
        for (int i = 0; i < 4; ++i) {
            unsigned short cb = f2b(acc[nt][i]);
            cr[nt][i] = b2f(cb);
            int r = r0 + i;
            if (r < M) C[(size_t)r * N + col] = cb;
        }
    }

    float alv[4], arv[4];
#pragma unroll
    for (int nt = 0; nt < 4; ++nt) {
        int c = (lane & 15) + nt * 16;
        alv[nt] = b2f(al[head * 64 + c]);
        arv[nt] = b2f(ar[head * 64 + c]);
    }
#pragma unroll
    for (int i = 0; i < 4; ++i) {
        float pl = 0.f, pr = 0.f;
#pragma unroll
        for (int nt = 0; nt < 4; ++nt) {
            pl += cr[nt][i] * alv[nt];
            pr += cr[nt][i] * arv[nt];
        }
#pragma unroll
        for (int o = 1; o < 16; o <<= 1) {
            pl += __shfl_xor(pl, o, 64);
            pr += __shfl_xor(pr, o, 64);
        }
        int r = r0 + i;
        if ((lane & 15) == 0 && r < M) {
            el[(size_t)r * H + head] = pl;
            er[(size_t)r * H + head] = pr;
        }
    }
}

// ---------------- layer-1 edges: block per dst, wave = head ----------------
// Lane layout in aggregation: lane = eg*16 + d16; group eg handles edges 4i+eg,
// lane covers dims [d16*4, d16*4+4) via 8B ushort4 loads. 4 edges/iteration.
__global__ __launch_bounds__(256) void k_edge1(const int* __restrict__ offs,
                        const int* __restrict__ csr_src,
                        const float* __restrict__ el, const float* __restrict__ er,
                        const unsigned short* __restrict__ feat,
                        const unsigned short* __restrict__ b1,
                        unsigned short* __restrict__ h1) {
    int node = blockIdx.x;
    int head = threadIdx.x >> 6, lane = threadIdx.x & 63;
    int eg = lane >> 4, d16 = lane & 15;
    int start = offs[node], end = offs[node + 1];
    float er_d = er[node * NH + head];
    float lsum = 0.f;
    float a0 = 0.f, a1 = 0.f, a2 = 0.f, a3 = 0.f;
    for (int base = start; base < end; base += 64) {
        int c = base + lane;
        float wgt = 0.f; int s = 0;
        if (c < end) {
            s = csr_src[c];
            float x = el[s * NH + head] + er_d;
            x = (x >= 0.f) ? x : 0.2f * x;
            wgt = __expf(x);      // |x| ~ O(1): shift-free softmax is exact enough
        }
        lsum += wgt;
        int cnt = end - base; if (cnt > 64) cnt = 64;
        int niter = (cnt + 3) >> 2;
#pragma unroll 4
        for (int i = 0; i < niter; ++i) {
            int idx = 4 * i + eg;
            float we = __shfl(wgt, idx, 64);
            int   se = __shfl(s, idx, 64);
            u16x4 fv = *(const u16x4*)&feat[(((size_t)se * NH + head) << 6) + (d16 << 2)];
            a0 += we * b2f(fv[0]);
            a1 += we * b2f(fv[1]);
            a2 += we * b2f(fv[2]);
            a3 += we * b2f(fv[3]);
        }
    }
#pragma unroll
    for (int o = 1; o < 64; o <<= 1) lsum += __shfl_xor(lsum, o, 64);
    a0 += __shfl_xor(a0, 16, 64); a0 += __shfl_xor(a0, 32, 64);
    a1 += __shfl_xor(a1, 16, 64); a1 += __shfl_xor(a1, 32, 64);
    a2 += __shfl_xor(a2, 16, 64); a2 += __shfl_xor(a2, 32, 64);
    a3 += __shfl_xor(a3, 16, 64); a3 += __shfl_xor(a3, 32, 64);
    if (eg == 0) {
        float inv = (lsum > 0.f) ? 1.f / lsum : 0.f;
        float o0 = a0 * inv + b2f(b1[head * 64 + d16 * 4 + 0]);
        float o1 = a1 * inv + b2f(b1[head * 64 + d16 * 4 + 1]);
        float o2 = a2 * inv + b2f(b1[head * 64 + d16 * 4 + 2]);
        float o3 = a3 * inv + b2f(b1[head * 64 + d16 * 4 + 3]);
        o0 = (o0 > 0.f) ? o0 : (__expf(o0) - 1.f);
        o1 = (o1 > 0.f) ? o1 : (__expf(o1) - 1.f);
        o2 = (o2 > 0.f) ? o2 : (__expf(o2) - 1.f);
        o3 = (o3 > 0.f) ? o3 : (__expf(o3) - 1.f);
        u16x4 r; r[0] = f2b(o0); r[1] = f2b(o1); r[2] = f2b(o2); r[3] = f2b(o3);
        *(u16x4*)&h1[(((size_t)node * NH + head) << 6) + d16 * 4] = r;
    }
}

// ---------------- layer-2 edges: wave per dst (H=1, D=64), same 4x16 layout ----------------
__global__ __launch_bounds__(256) void k_edge2(const int* __restrict__ offs,
                        const int* __restrict__ csr_src,
                        const float* __restrict__ el, const float* __restrict__ er,
                        const unsigned short* __restrict__ feat,
                        const unsigned short* __restrict__ b2,
                        void* __restrict__ out, const int* __restrict__ flagp) {
    int wave = threadIdx.x >> 6, lane = threadIdx.x & 63;
    int node = blockIdx.x * 4 + wave;
    if (node >= NN) return;
    int eg = lane >> 4, d16 = lane & 15;
    int isbf = flagp[0];
    int start = offs[node], end = offs[node + 1];
    float er_d = er[node];
    float lsum = 0.f;
    float a0 = 0.f, a1 = 0.f, a2 = 0.f, a3 = 0.f;
    for (int base = start; base < end; base += 64) {
        int c = base + lane;
        float wgt = 0.f; int s = 0;
        if (c < end) {
            s = csr_src[c];
            float x = el[s] + er_d;
            x = (x >= 0.f) ? x : 0.2f * x;
            wgt = __expf(x);
        }
        lsum += wgt;
        int cnt = end - base; if (cnt > 64) cnt = 64;
        int niter = (cnt + 3) >> 2;
#pragma unroll 4
        for (int i = 0; i < niter; ++i) {
            int idx = 4 * i + eg;
            float we = __shfl(wgt, idx, 64);
            int   se = __shfl(s, idx, 64);
            u16x4 fv = *(const u16x4*)&feat[((size_t)se << 6) + (d16 << 2)];
            a0 += we * b2f(fv[0]);
            a1 += we * b2f(fv[1]);
            a2 += we * b2f(fv[2]);
            a3 += we * b2f(fv[3]);
        }
    }
#pragma unroll
    for (int o = 1; o < 64; o <<= 1) lsum += __shfl_xor(lsum, o, 64);
    a0 += __shfl_xor(a0, 16, 64); a0 += __shfl_xor(a0, 32, 64);
    a1 += __shfl_xor(a1, 16, 64); a1 += __shfl_xor(a1, 32, 64);
    a2 += __shfl_xor(a2, 16, 64); a2 += __shfl_xor(a2, 32, 64);
    a3 += __shfl_xor(a3, 16, 64); a3 += __shfl_xor(a3, 32, 64);
    if (eg == 0) {
        float inv = (lsum > 0.f) ? 1.f / lsum : 0.f;
        float o0 = a0 * inv + b2f(b2[d16 * 4 + 0]);
        float o1 = a1 * inv + b2f(b2[d16 * 4 + 1]);
        float o2 = a2 * inv + b2f(b2[d16 * 4 + 2]);
        float o3 = a3 * inv + b2f(b2[d16 * 4 + 3]);
        size_t ob = ((size_t)node << 6) + d16 * 4;
        if (isbf) {
            u16x4 r; r[0] = f2b(o0); r[1] = f2b(o1); r[2] = f2b(o2); r[3] = f2b(o3);
            *(u16x4*)&((unsigned short*)out)[ob] = r;
        } else {
            float4 r; r.x = o0; r.y = o1; r.z = o2; r.w = o3;
            *(float4*)&((float*)out)[ob] = r;
        }
    }
}

extern "C" void kernel_launch(void* const* d_in, const int* in_sizes, int n_in,
                              void* d_out, int out_size, void* d_ws, size_t ws_size,
                              hipStream_t stream) {
    const void* h   = d_in[0];
    const int*  src = (const int*)d_in[1];
    const int*  dst = (const int*)d_in[2];
    const void* W1  = d_in[3];
    const void* al1 = d_in[4];
    const void* ar1 = d_in[5];
    const void* b1  = d_in[6];
    const void* W2  = d_in[7];
    const void* al2 = d_in[8];
    const void* ar2 = d_in[9];
    const void* b2  = d_in[10];

    char* w = (char*)d_ws;
    size_t off = 0;
    auto alloc = [&](size_t bytes) -> void* {
        void* p = w + off;
        off = (off + bytes + 255) & ~(size_t)255;
        return p;
    };
    int* flag               = (int*)alloc(4);
    int* deg                = (int*)alloc(NN * 4);
    int* cursor             = (int*)alloc(NN * 4);
    int* offs               = (int*)alloc((NN + 1) * 4);
    int* csr_src            = (int*)alloc(NE * 4);
    unsigned short* canon   = (unsigned short*)alloc(960 * 2);
    unsigned short* W1T     = (unsigned short*)alloc(256 * 256 * 2);
    unsigned short* W2T     = (unsigned short*)alloc(64 * 256 * 2);
    unsigned short* feat1   = (unsigned short*)alloc((size_t)NN * 256 * 2);
    float* el1              = (float*)alloc(NN * NH * 4);
    float* er1              = (float*)alloc(NN * NH * 4);
    unsigned short* h1      = (unsigned short*)alloc((size_t)NN * 256 * 2);
    unsigned short* feat2   = (unsigned short*)alloc((size_t)NN * 64 * 2);
    float* el2              = (float*)alloc(NN * 4);
    float* er2              = (float*)alloc(NN * 4);
    (void)ws_size; (void)in_sizes; (void)n_in; (void)out_size;

    unsigned short* cal1 = canon + 0;
    unsigned short* car1 = canon + 256;
    unsigned short* cb1  = canon + 512;
    unsigned short* cal2 = canon + 768;
    unsigned short* car2 = canon + 832;
    unsigned short* cb2  = canon + 896;

    k_detect<<<1, 256, 0, stream>>>((const unsigned short*)h, flag);

    hipMemsetAsync(deg, 0, NN * 4, stream);
    k_deg<<<(NE + 255) / 256, 256, 0, stream>>>(dst, deg, NE);
    k_scan<<<1, 256, 0, stream>>>(deg, offs, cursor, NN);
    k_scatter<<<(NE + 255) / 256, 256, 0, stream>>>(src, dst, cursor, csr_src, NE);

    k_small<<<4, 256, 0, stream>>>(al1, ar1, b1, al2, ar2, b2, canon, flag);
    k_transpose_all<<<(65536 + 16384 + 255) / 256, 256, 0, stream>>>(W1, W2, W1T, W2T, flag);

    k_gemm<<<dim3((NN + 63) / 64, 4), 256, 0, stream>>>(h, W1T, feat1, el1, er1,
                                                        cal1, car1, NN, 256, 256, NH, flag);
    k_edge1<<<NN, 256, 0, stream>>>(offs, csr_src, el1, er1, feat1, cb1, h1);

    k_gemm<<<dim3((NN + 63) / 64, 1), 256, 0, stream>>>(h1, W2T, feat2, el2, er2,
                                                        cal2, car2, NN, 64, 256, 1, nullptr);
    k_edge2<<<(NN + 3) / 4, 256, 0, stream>>>(offs, csr_src, el2, er2, feat2, cb2, d_out, flag);
}